// Round 12
// baseline (198.123 us; speedup 1.0000x reference)
//
#include <hip/hip_runtime.h>

typedef float fv2 __attribute__((ext_vector_type(2)));

#define KC 256                   // codebook size
#define NROWS (8*64*64*64/4)     // 524288 rows of dim 4
#define RPT 2                    // rows per thread
#define TPB 256                  // threads per block
#define NB (NROWS/(TPB*RPT))     // 1024 blocks -> 4 waves/SIMD
#define NG (KC/4)                // 64 chunks of 4 centers
#define PASSES 12                // probe scan repetitions

// One full codebook scan: chunk-max tracking, rows (a,b) packed into fv2
// halves -> v_pk_fma_f32 / v_pk_max_f32. Per-half bit-identical to scalar
// v_fma/v_max chains (proven absmax 0 in rounds 9 and 11).
__device__ __forceinline__ void scan_once(const float* __restrict__ center,
                                          const float4* smh4,
                                          const fv2 Xx, const fv2 Xy,
                                          const fv2 Xz, const fv2 Xw,
                                          float& bpa, float& bpb,
                                          int& bca, int& bcb) {
#pragma unroll 2
    for (int g = 0; g < NG; ++g) {
        // 16 consecutive codebook floats, uniform index -> s_load_dwordx16.
        float cv[16];
#pragma unroll
        for (int j = 0; j < 16; ++j) cv[j] = center[16 * g + j];
        const float4 m = smh4[g];  // uniform ds_read_b128 broadcast

        fv2 q[4];
#pragma unroll
        for (int j = 0; j < 4; ++j) {
            const float mh = (j == 0) ? m.x : (j == 1) ? m.y : (j == 2) ? m.z : m.w;
            const fv2 Cx = {cv[4*j+0], cv[4*j+0]};
            const fv2 Cy = {cv[4*j+1], cv[4*j+1]};
            const fv2 Cz = {cv[4*j+2], cv[4*j+2]};
            const fv2 Cw = {cv[4*j+3], cv[4*j+3]};
            const fv2 MH = {mh, mh};
            // Same per-row fma chain order as every passing round.
            fv2 t = __builtin_elementwise_fma(Xx, Cx, MH);
            t = __builtin_elementwise_fma(Xy, Cy, t);
            t = __builtin_elementwise_fma(Xz, Cz, t);
            t = __builtin_elementwise_fma(Xw, Cw, t);
            q[j] = t;
        }
        const fv2 mm = __builtin_elementwise_max(
            __builtin_elementwise_max(q[0], q[1]),
            __builtin_elementwise_max(q[2], q[3]));
        // strict '>': earliest chunk wins ties (argmin-first semantics)
        const bool ta = mm.x > bpa; bpa = ta ? mm.x : bpa; bca = ta ? g : bca;
        const bool tb = mm.y > bpb; bpb = tb ? mm.y : bpb; bcb = tb ? g : bcb;
    }
}

// ---------------- candidate: RPT=2 + pk, single scan + resolve ----------------
__global__ __launch_bounds__(TPB) void vq_main(const float* __restrict__ x,
                                               const float* __restrict__ center,
                                               float* __restrict__ out) {
    __shared__ float4 smh4[NG];    // -0.5*||c||^2, packed 4 per float4

    const int tid = threadIdx.x;
    {
        float4 c = reinterpret_cast<const float4*>(center)[tid];
        reinterpret_cast<float*>(smh4)[tid] =
            -0.5f * (c.x * c.x + c.y * c.y + c.z * c.z + c.w * c.w);
    }
    __syncthreads();

    const int base = blockIdx.x * (TPB * RPT) + tid;
    const float4* x4 = reinterpret_cast<const float4*>(x);
    const float4 xa = x4[base];
    const float4 xb = x4[base + TPB];
    const fv2 Xx = {xa.x, xb.x}, Xy = {xa.y, xb.y},
              Xz = {xa.z, xb.z}, Xw = {xa.w, xb.w};

    float bpa = -__builtin_inff(), bpb = -__builtin_inff();
    int bca = 0, bcb = 0;

    scan_once(center, smh4, Xx, Xy, Xz, Xw, bpa, bpb, bca, bcb);

    // Self-contained bit-exact resolve (round-9 proven): recompute winning
    // chunk's 4 scores from the SAME mh bits (smh4) with the same scalar fma
    // chain (== pk per-half bits), pick lowest j achieving the local max.
    auto resolve = [&](const float4 xv, const int bc) -> float4 {
        const float4* c4 = reinterpret_cast<const float4*>(center);
        float4 cf[4];
#pragma unroll
        for (int j = 0; j < 4; ++j) cf[j] = c4[4 * bc + j];  // L1-resident
        const float4 m = smh4[bc];   // same bits as main loop
        float p[4];
#pragma unroll
        for (int j = 0; j < 4; ++j) {
            const float mh = (j == 0) ? m.x : (j == 1) ? m.y : (j == 2) ? m.z : m.w;
            float t = fmaf(xv.x, cf[j].x, mh);
            t = fmaf(xv.y, cf[j].y, t);
            t = fmaf(xv.z, cf[j].z, t);
            t = fmaf(xv.w, cf[j].w, t);
            p[j] = t;
        }
        const float mx = fmaxf(fmaxf(fmaxf(p[0], p[1]), p[2]), p[3]);
        float4 w = cf[3];
        if (p[2] == mx) w = cf[2];   // descending: lowest matching j wins
        if (p[1] == mx) w = cf[1];
        if (p[0] == mx) w = cf[0];
        return w;
    };

    float4* o4 = reinterpret_cast<float4*>(out);
    o4[base]       = resolve(xa, bca);
    o4[base + TPB] = resolve(xb, bcb);
}

// ---------------- probe: 12x identical scan, no stores (diagnostic) ----------
// Purpose: surface the scan loop in rocprof (dur > harness fills) and measure
// its true marginal cost: scan_us ~= (dur_us - ~3) / 12. Opaque asm between
// passes defeats cross-pass CSE; final asm sinks prevent DCE (rule #17).
__global__ __launch_bounds__(TPB) void vq_probe(const float* __restrict__ x,
                                                const float* __restrict__ center) {
    __shared__ float4 smh4[NG];

    const int tid = threadIdx.x;
    {
        float4 c = reinterpret_cast<const float4*>(center)[tid];
        reinterpret_cast<float*>(smh4)[tid] =
            -0.5f * (c.x * c.x + c.y * c.y + c.z * c.z + c.w * c.w);
    }
    __syncthreads();

    const int base = blockIdx.x * (TPB * RPT) + tid;
    const float4* x4 = reinterpret_cast<const float4*>(x);
    const float4 xa = x4[base];
    const float4 xb = x4[base + TPB];

    float ax = xa.x, ay = xa.y, az = xa.z, aw = xa.w;
    float bx = xb.x, by = xb.y, bz = xb.z, bw = xb.w;

    float bpa = -__builtin_inff(), bpb = -__builtin_inff();
    int bca = 0, bcb = 0;

#pragma unroll 1
    for (int pass = 0; pass < PASSES; ++pass) {
        // Opaque identity on the x registers: pass p+1's scan can't be CSE'd
        // against pass p's (compiler must recompute every fma chain).
        asm volatile("" : "+v"(ax), "+v"(ay), "+v"(az), "+v"(aw),
                          "+v"(bx), "+v"(by), "+v"(bz), "+v"(bw));
        const fv2 Xx = {ax, bx}, Xy = {ay, by}, Xz = {az, bz}, Xw = {aw, bw};
        scan_once(center, smh4, Xx, Xy, Xz, Xw, bpa, bpb, bca, bcb);
    }
    // Keep results alive without storing.
    asm volatile("" :: "v"(bpa), "v"(bpb), "v"(bca), "v"(bcb));
}

extern "C" void kernel_launch(void* const* d_in, const int* in_sizes, int n_in,
                              void* d_out, int out_size, void* d_ws, size_t ws_size,
                              hipStream_t stream) {
    const float* x      = (const float*)d_in[0];
    const float* center = (const float*)d_in[1];
    float* out = (float*)d_out;

    vq_main<<<NB, TPB, 0, stream>>>(x, center, out);
    vq_probe<<<NB, TPB, 0, stream>>>(x, center);   // diagnostic only; no output
}

// Round 13
// 45.860 us; speedup vs baseline: 4.3202x; 4.3202x over previous
//
#include <hip/hip_runtime.h>

typedef float fv2 __attribute__((ext_vector_type(2)));

#define KC 256                   // codebook size
#define NROWS (8*64*64*64/4)     // 524288 rows of dim 4
#define RPT 2                    // rows per thread
#define TPB 256                  // threads per block
#define NB (NROWS/(TPB*RPT))     // 1024 blocks -> 4 waves/SIMD
#define NG (KC/4)                // 64 chunks of 4 centers
#define WSTRIDE 20               // floats per chunk in the packed table

// Packed table, per chunk g (20 floats, built once by vq_prep):
// [0..7]  = {c0.x,c1.x}{c0.y,c1.y}{c0.z,c1.z}{c0.w,c1.w}   (center pair 0,1)
// [8..15] = {c2.x,c3.x}{c2.y,c3.y}{c2.z,c3.z}{c2.w,c3.w}   (center pair 2,3)
// [16..19]= {mh0,mh1,mh2,mh3},  mh = -0.5*||c||^2  (single computation site)
__global__ void vq_prep(const float* __restrict__ center, float* __restrict__ wst) {
    const int g = threadIdx.x;                       // 64 threads, 1 block
    const float4* c4 = reinterpret_cast<const float4*>(center);
    const float4 c0 = c4[4*g+0], c1 = c4[4*g+1], c2 = c4[4*g+2], c3 = c4[4*g+3];
    float* o = wst + WSTRIDE * g;
    o[0]=c0.x;  o[1]=c1.x;  o[2]=c0.y;  o[3]=c1.y;
    o[4]=c0.z;  o[5]=c1.z;  o[6]=c0.w;  o[7]=c1.w;
    o[8]=c2.x;  o[9]=c3.x;  o[10]=c2.y; o[11]=c3.y;
    o[12]=c2.z; o[13]=c3.z; o[14]=c2.w; o[15]=c3.w;
    o[16] = -0.5f*(c0.x*c0.x + c0.y*c0.y + c0.z*c0.z + c0.w*c0.w);
    o[17] = -0.5f*(c1.x*c1.x + c1.y*c1.y + c1.z*c1.z + c1.w*c1.w);
    o[18] = -0.5f*(c2.x*c2.x + c2.y*c2.y + c2.z*c2.z + c2.w*c2.w);
    o[19] = -0.5f*(c3.x*c3.x + c3.y*c3.y + c3.z*c3.z + c3.w*c3.w);
}

// Packed f32 ops with the table operand FORCED into an SGPR pair (uniform):
// zero splat movs in the loop. Pure-VALU asm: no memory/waitcnt semantics,
// compiler owns the s_load and inserts lgkmcnt via the "s" data-dependence.
__device__ __forceinline__ fv2 pk_mul_vs(fv2 a, fv2 bs) {
    fv2 d; asm("v_pk_mul_f32 %0, %1, %2" : "=v"(d) : "v"(a), "s"(bs)); return d;
}
__device__ __forceinline__ void pk_fma_vs(fv2& acc, fv2 a, fv2 bs) {
    asm("v_pk_fma_f32 %0, %1, %2, %0" : "+v"(acc) : "v"(a), "s"(bs));
}
__device__ __forceinline__ void pk_add_vs(fv2& acc, fv2 bs) {
    asm("v_pk_add_f32 %0, %0, %1" : "+v"(acc) : "s"(bs));
}

// Score chain (both sites use EXACTLY this order): t = x.x*c.x; t=fma(x.y,c.y,t);
// t=fma(x.z,c.z,t); t=fma(x.w,c.w,t); t=t+mh.  pk per-half == scalar ops.
__global__ __launch_bounds__(TPB) void vq_main(const float* __restrict__ x,
                                               const float* __restrict__ center,
                                               const float* __restrict__ wst,
                                               float* __restrict__ out) {
    const int base = blockIdx.x * (TPB * RPT) + threadIdx.x;
    const float4* x4 = reinterpret_cast<const float4*>(x);
    const float4 xa = x4[base];
    const float4 xb = x4[base + TPB];

    // Per-row splats, built ONCE (hoisted out of the 64-chunk loop).
    const fv2 Ax = {xa.x, xa.x}, Ay = {xa.y, xa.y}, Az = {xa.z, xa.z}, Aw = {xa.w, xa.w};
    const fv2 Bx = {xb.x, xb.x}, By = {xb.y, xb.y}, Bz = {xb.z, xb.z}, Bw = {xb.w, xb.w};

    float bpa = -__builtin_inff(), bpb = -__builtin_inff();
    int bca = 0, bcb = 0;

#pragma unroll 2
    for (int g = 0; g < NG; ++g) {
        const fv2* wp = reinterpret_cast<const fv2*>(wst + WSTRIDE * g);
        const fv2 c01x = wp[0], c01y = wp[1], c01z = wp[2], c01w = wp[3];
        const fv2 c23x = wp[4], c23y = wp[5], c23z = wp[6], c23w = wp[7];
        const fv2 mh01 = wp[8], mh23 = wp[9];

        // row a
        fv2 pa01 = pk_mul_vs(Ax, c01x);
        pk_fma_vs(pa01, Ay, c01y); pk_fma_vs(pa01, Az, c01z); pk_fma_vs(pa01, Aw, c01w);
        pk_add_vs(pa01, mh01);
        fv2 pa23 = pk_mul_vs(Ax, c23x);
        pk_fma_vs(pa23, Ay, c23y); pk_fma_vs(pa23, Az, c23z); pk_fma_vs(pa23, Aw, c23w);
        pk_add_vs(pa23, mh23);
        // row b
        fv2 pb01 = pk_mul_vs(Bx, c01x);
        pk_fma_vs(pb01, By, c01y); pk_fma_vs(pb01, Bz, c01z); pk_fma_vs(pb01, Bw, c01w);
        pk_add_vs(pb01, mh01);
        fv2 pb23 = pk_mul_vs(Bx, c23x);
        pk_fma_vs(pb23, By, c23y); pk_fma_vs(pb23, Bz, c23z); pk_fma_vs(pb23, Bw, c23w);
        pk_add_vs(pb23, mh23);

        // chunk max + strict-'>' tracking (earliest chunk wins ties).
        const fv2 ma2 = __builtin_elementwise_max(pa01, pa23);   // v_pk_max_f32
        const float ma = fmaxf(ma2.x, ma2.y);
        bca = (ma > bpa) ? g : bca;        // g<=63: inline const in cndmask src0
        bpa = fmaxf(bpa, ma);
        const fv2 mb2 = __builtin_elementwise_max(pb01, pb23);
        const float mb = fmaxf(mb2.x, mb2.y);
        bcb = (mb > bpb) ? g : bcb;
        bpb = fmaxf(bpb, mb);
    }

    // Resolve: recompute winning chunk's 4 scores with the SAME chain and the
    // SAME mh bits (table, single site) -> bit-identical to the loop's values;
    // bp (max of those exact bits) matches exactly. Lowest matching j wins.
    auto resolve = [&](const float4 xv, const int bc, const float bp) -> float4 {
        const float4* c4 = reinterpret_cast<const float4*>(center);
        float4 cf[4];
#pragma unroll
        for (int j = 0; j < 4; ++j) cf[j] = c4[4 * bc + j];          // L1-resident
        const float4 mh = *reinterpret_cast<const float4*>(wst + WSTRIDE * bc + 16);
        float p[4];
#pragma unroll
        for (int j = 0; j < 4; ++j) {
            const float mhj = (j==0) ? mh.x : (j==1) ? mh.y : (j==2) ? mh.z : mh.w;
            float t = xv.x * cf[j].x;          // mirror of pk chain (mul first,
            t = fmaf(xv.y, cf[j].y, t);        //  mh added last)
            t = fmaf(xv.z, cf[j].z, t);
            t = fmaf(xv.w, cf[j].w, t);
            p[j] = t + mhj;
        }
        float4 w = cf[3];
        if (p[2] == bp) w = cf[2];   // descending: lowest matching j wins
        if (p[1] == bp) w = cf[1];
        if (p[0] == bp) w = cf[0];
        return w;
    };

    float4* o4 = reinterpret_cast<float4*>(out);
    o4[base]       = resolve(xa, bca, bpa);
    o4[base + TPB] = resolve(xb, bcb, bpb);
}

// ---------------- fallback (ws too small): round-2 LDS kernel (proven) -------
__global__ __launch_bounds__(TPB) void vq_lds(const float* __restrict__ x,
                                              const float* __restrict__ center,
                                              float* __restrict__ out) {
    __shared__ float4 sc[KC];
    __shared__ float smh[KC];
    const int tid = threadIdx.x;
    {
        float4 c = reinterpret_cast<const float4*>(center)[tid];
        sc[tid] = c;
        smh[tid] = -0.5f * (c.x*c.x + c.y*c.y + c.z*c.z + c.w*c.w);
    }
    __syncthreads();
    const int base = blockIdx.x * (TPB * RPT) + tid;
    const float4* x4 = reinterpret_cast<const float4*>(x);
    float4 xa = x4[base], xb = x4[base + TPB];
    float bpa = -__builtin_inff(), bpb = -__builtin_inff();
    int bka = 0, bkb = 0;
#pragma unroll 8
    for (int k = 0; k < KC; ++k) {
        float4 c = sc[k];
        float mh = smh[k];
        float pa = fmaf(xa.x, c.x, mh); pa = fmaf(xa.y, c.y, pa);
        pa = fmaf(xa.z, c.z, pa);       pa = fmaf(xa.w, c.w, pa);
        if (pa > bpa) { bpa = pa; bka = k; }
        float pb = fmaf(xb.x, c.x, mh); pb = fmaf(xb.y, c.y, pb);
        pb = fmaf(xb.z, c.z, pb);       pb = fmaf(xb.w, c.w, pb);
        if (pb > bpb) { bpb = pb; bkb = k; }
    }
    reinterpret_cast<float4*>(out)[base]       = sc[bka];
    reinterpret_cast<float4*>(out)[base + TPB] = sc[bkb];
}

extern "C" void kernel_launch(void* const* d_in, const int* in_sizes, int n_in,
                              void* d_out, int out_size, void* d_ws, size_t ws_size,
                              hipStream_t stream) {
    const float* x      = (const float*)d_in[0];
    const float* center = (const float*)d_in[1];
    float* out = (float*)d_out;

    if (ws_size >= NG * WSTRIDE * sizeof(float)) {
        float* wst = (float*)d_ws;
        vq_prep<<<1, NG, 0, stream>>>(center, wst);
        vq_main<<<NB, TPB, 0, stream>>>(x, center, wst, out);
    } else {
        vq_lds<<<NB, TPB, 0, stream>>>(x, center, out);
    }
}

// Round 14
// 31.035 us; speedup vs baseline: 6.3839x; 1.4777x over previous
//
#include <hip/hip_runtime.h>

typedef float fv2 __attribute__((ext_vector_type(2)));

#define KC 256                   // codebook size
#define NROWS (8*64*64*64/4)     // 524288 rows of dim 4
#define RPT 2                    // rows per thread
#define TPB 256                  // threads per block
#define NB (NROWS/(TPB*RPT))     // 1024 blocks -> 4 waves/SIMD
#define NG (KC/4)                // 64 chunks of 4 centers
#define WSTRIDE 20               // floats per chunk in the packed table

// Packed table, per chunk g (20 floats, built once by vq_prep):
// [0..7]  = {c0.x,c1.x}{c0.y,c1.y}{c0.z,c1.z}{c0.w,c1.w}
// [8..15] = {c2.x,c3.x}{c2.y,c3.y}{c2.z,c3.z}{c2.w,c3.w}
// [16..19]= {mh0,mh1},{mh2,mh3},  mh = -0.5*||c||^2 (single computation site)
// Pairs are memory-adjacent -> scalarized loads put each fv2 in consecutive
// SGPRs, usable by v_pk_* without splat movs (builtins only, no inline asm).
__global__ void vq_prep(const float* __restrict__ center, float* __restrict__ wst) {
    const int g = threadIdx.x;                       // 64 threads, 1 block
    const float4* c4 = reinterpret_cast<const float4*>(center);
    const float4 c0 = c4[4*g+0], c1 = c4[4*g+1], c2 = c4[4*g+2], c3 = c4[4*g+3];
    float* o = wst + WSTRIDE * g;
    o[0]=c0.x;  o[1]=c1.x;  o[2]=c0.y;  o[3]=c1.y;
    o[4]=c0.z;  o[5]=c1.z;  o[6]=c0.w;  o[7]=c1.w;
    o[8]=c2.x;  o[9]=c3.x;  o[10]=c2.y; o[11]=c3.y;
    o[12]=c2.z; o[13]=c3.z; o[14]=c2.w; o[15]=c3.w;
    o[16] = -0.5f*(c0.x*c0.x + c0.y*c0.y + c0.z*c0.z + c0.w*c0.w);
    o[17] = -0.5f*(c1.x*c1.x + c1.y*c1.y + c1.z*c1.z + c1.w*c1.w);
    o[18] = -0.5f*(c2.x*c2.x + c2.y*c2.y + c2.z*c2.z + c2.w*c2.w);
    o[19] = -0.5f*(c3.x*c3.x + c3.y*c3.y + c3.z*c3.z + c3.w*c3.w);
}

// Score chain (BOTH sites use exactly this order, per half):
//   t = x.x*c.x; t = fma(x.y,c.y,t); t = fma(x.z,c.z,t); t = fma(x.w,c.w,t);
//   p = t + mh.
__global__ __launch_bounds__(TPB) void vq_main(const float* __restrict__ x,
                                               const float* __restrict__ center,
                                               const float* __restrict__ wst,
                                               float* __restrict__ out) {
    const int base = blockIdx.x * (TPB * RPT) + threadIdx.x;
    const float4* x4 = reinterpret_cast<const float4*>(x);
    const float4 xa = x4[base];
    const float4 xb = x4[base + TPB];

    // Per-row splats, built ONCE (outside the 64-chunk loop).
    const fv2 Ax = {xa.x, xa.x}, Ay = {xa.y, xa.y}, Az = {xa.z, xa.z}, Aw = {xa.w, xa.w};
    const fv2 Bx = {xb.x, xb.x}, By = {xb.y, xb.y}, Bz = {xb.z, xb.z}, Bw = {xb.w, xb.w};

    float bpa = -__builtin_inff(), bpb = -__builtin_inff();
    int bca = 0, bcb = 0;

#pragma unroll 4
    for (int g = 0; g < NG; ++g) {
        // 10 memory-adjacent fv2 pairs, uniform address -> scalar loads.
        const fv2* wp = reinterpret_cast<const fv2*>(wst + WSTRIDE * g);
        const fv2 c01x = wp[0], c01y = wp[1], c01z = wp[2], c01w = wp[3];
        const fv2 c23x = wp[4], c23y = wp[5], c23z = wp[6], c23w = wp[7];
        const fv2 mh01 = wp[8], mh23 = wp[9];

        // row a, centers {0,1} and {2,3}
        fv2 qa01 = Ax * c01x;
        qa01 = __builtin_elementwise_fma(Ay, c01y, qa01);
        qa01 = __builtin_elementwise_fma(Az, c01z, qa01);
        qa01 = __builtin_elementwise_fma(Aw, c01w, qa01);
        qa01 = qa01 + mh01;
        fv2 qa23 = Ax * c23x;
        qa23 = __builtin_elementwise_fma(Ay, c23y, qa23);
        qa23 = __builtin_elementwise_fma(Az, c23z, qa23);
        qa23 = __builtin_elementwise_fma(Aw, c23w, qa23);
        qa23 = qa23 + mh23;
        // row b
        fv2 qb01 = Bx * c01x;
        qb01 = __builtin_elementwise_fma(By, c01y, qb01);
        qb01 = __builtin_elementwise_fma(Bz, c01z, qb01);
        qb01 = __builtin_elementwise_fma(Bw, c01w, qb01);
        qb01 = qb01 + mh01;
        fv2 qb23 = Bx * c23x;
        qb23 = __builtin_elementwise_fma(By, c23y, qb23);
        qb23 = __builtin_elementwise_fma(Bz, c23z, qb23);
        qb23 = __builtin_elementwise_fma(Bw, c23w, qb23);
        qb23 = qb23 + mh23;

        // chunk max (exactly associative -> same bits as any max order).
        const fv2 ma2 = __builtin_elementwise_max(qa01, qa23);  // v_pk_max_f32
        const float ma = fmaxf(ma2.x, ma2.y);
        bca = (ma > bpa) ? g : bca;    // strict '>': earliest chunk wins ties
        bpa = fmaxf(bpa, ma);
        const fv2 mb2 = __builtin_elementwise_max(qb01, qb23);
        const float mb = fmaxf(mb2.x, mb2.y);
        bcb = (mb > bpb) ? g : bcb;
        bpb = fmaxf(bpb, mb);
    }

    // Resolve: recompute winning chunk's 4 scores with the SAME chain and the
    // SAME mh bits (table, single site) -> bit-identical to the loop's values;
    // bp is the max of exactly those bits. Lowest matching j wins.
    auto resolve = [&](const float4 xv, const int bc, const float bp) -> float4 {
        const float4* c4 = reinterpret_cast<const float4*>(center);
        float4 cf[4];
#pragma unroll
        for (int j = 0; j < 4; ++j) cf[j] = c4[4 * bc + j];          // L1-resident
        const float4 mh = *reinterpret_cast<const float4*>(wst + WSTRIDE * bc + 16);
        float p[4];
#pragma unroll
        for (int j = 0; j < 4; ++j) {
            const float mhj = (j==0) ? mh.x : (j==1) ? mh.y : (j==2) ? mh.z : mh.w;
            float t = xv.x * cf[j].x;          // mirror of pk chain per half
            t = fmaf(xv.y, cf[j].y, t);
            t = fmaf(xv.z, cf[j].z, t);
            t = fmaf(xv.w, cf[j].w, t);
            p[j] = t + mhj;
        }
        float4 w = cf[3];
        if (p[2] == bp) w = cf[2];   // descending: lowest matching j wins
        if (p[1] == bp) w = cf[1];
        if (p[0] == bp) w = cf[0];
        return w;
    };

    float4* o4 = reinterpret_cast<float4*>(out);
    o4[base]       = resolve(xa, bca, bpa);
    o4[base + TPB] = resolve(xb, bcb, bpb);
}

// ---------------- fallback (ws too small): round-2 LDS kernel (proven) -------
__global__ __launch_bounds__(TPB) void vq_lds(const float* __restrict__ x,
                                              const float* __restrict__ center,
                                              float* __restrict__ out) {
    __shared__ float4 sc[KC];
    __shared__ float smh[KC];
    const int tid = threadIdx.x;
    {
        float4 c = reinterpret_cast<const float4*>(center)[tid];
        sc[tid] = c;
        smh[tid] = -0.5f * (c.x*c.x + c.y*c.y + c.z*c.z + c.w*c.w);
    }
    __syncthreads();
    const int base = blockIdx.x * (TPB * RPT) + tid;
    const float4* x4 = reinterpret_cast<const float4*>(x);
    float4 xa = x4[base], xb = x4[base + TPB];
    float bpa = -__builtin_inff(), bpb = -__builtin_inff();
    int bka = 0, bkb = 0;
#pragma unroll 8
    for (int k = 0; k < KC; ++k) {
        float4 c = sc[k];
        float mh = smh[k];
        float pa = fmaf(xa.x, c.x, mh); pa = fmaf(xa.y, c.y, pa);
        pa = fmaf(xa.z, c.z, pa);       pa = fmaf(xa.w, c.w, pa);
        if (pa > bpa) { bpa = pa; bka = k; }
        float pb = fmaf(xb.x, c.x, mh); pb = fmaf(xb.y, c.y, pb);
        pb = fmaf(xb.z, c.z, pb);       pb = fmaf(xb.w, c.w, pb);
        if (pb > bpb) { bpb = pb; bkb = k; }
    }
    reinterpret_cast<float4*>(out)[base]       = sc[bka];
    reinterpret_cast<float4*>(out)[base + TPB] = sc[bkb];
}

extern "C" void kernel_launch(void* const* d_in, const int* in_sizes, int n_in,
                              void* d_out, int out_size, void* d_ws, size_t ws_size,
                              hipStream_t stream) {
    const float* x      = (const float*)d_in[0];
    const float* center = (const float*)d_in[1];
    float* out = (float*)d_out;

    if (ws_size >= NG * WSTRIDE * sizeof(float)) {
        float* wst = (float*)d_ws;
        vq_prep<<<1, NG, 0, stream>>>(center, wst);
        vq_main<<<NB, TPB, 0, stream>>>(x, center, wst, out);
    } else {
        vq_lds<<<NB, TPB, 0, stream>>>(x, center, out);
    }
}